// Round 1
// baseline (1863.601 us; speedup 1.0000x reference)
//
#include <hip/hip_runtime.h>

#define TS 262144          // TABLE_SIZE = 2^18
#define TMASK (TS - 1)
#define P2 2654435761u
#define P3 805459861u

// RES[l] = floor(16 * (512/16)^(l/15) + 1e-6)
__device__ __constant__ int c_res[16] = {16, 20, 25, 32, 40, 50, 64, 80,
                                         101, 128, 161, 203, 256, 322, 406, 512};

// Pre-pass: transpose tables [F,T] -> [T,F] (float2) into workspace.
// ws layout (float2 units): [0,4096) dense grid, [4096, 4096+15*TS) hash levels 1..15.
__global__ __launch_bounds__(256) void xpose_kernel(
    const float* __restrict__ dense, const float* __restrict__ tables,
    float2* __restrict__ ws) {
  int i = blockIdx.x * 256 + threadIdx.x;
  const int total = 15 * TS;
  if (i < total) {
    int l = i >> 18;
    int h = i & TMASK;
    const float* t = tables + (size_t)l * (2 * TS);
    ws[4096 + i] = make_float2(t[h], t[TS + h]);
  } else {
    int j = i - total;
    if (j < 4096) ws[j] = make_float2(dense[j], dense[4096 + j]);
  }
}

// Main kernel: thread -> (point, level). lane = pin*16 + lvl so the float2
// output store is fully coalesced across the block.
template <bool XP>
__global__ __launch_bounds__(256) void encode_kernel(
    const float* __restrict__ coords,
    const float* __restrict__ dense,       // original [2,16,16,16] (fallback)
    const float* __restrict__ tables,      // original [15,2,TS]    (fallback)
    const float2* __restrict__ xtab,       // transposed ws (XP path)
    float2* __restrict__ out, int npts) {
  __shared__ float s_c[48];   // 16 points x 3 coords
  __shared__ int s_res[16];
  const int tid = threadIdx.x;
  const int lvl = tid & 15;
  const int pin = tid >> 4;
  const int pbase = blockIdx.x * 16;

  if (tid < 48) {
    int gi = pbase * 3 + tid;
    s_c[tid] = (gi < npts * 3) ? coords[gi] : 0.0f;
  }
  if (tid < 16) s_res[tid] = c_res[tid];
  __syncthreads();

  const int n = pbase + pin;
  if (n >= npts) return;

  const float cx = s_c[pin * 3 + 0];
  const float cy = s_c[pin * 3 + 1];
  const float cz = s_c[pin * 3 + 2];
  const int res = s_res[lvl];
  const int r1 = res - 1;
  const float rm1 = (float)r1;

  // pos = clip((c+1)*0.5*(res-1), 0, res-1); i0 = floor(pos); w = frac
  float px = fminf(fmaxf((cx + 1.0f) * 0.5f * rm1, 0.0f), rm1);
  float py = fminf(fmaxf((cy + 1.0f) * 0.5f * rm1, 0.0f), rm1);
  float pz = fminf(fmaxf((cz + 1.0f) * 0.5f * rm1, 0.0f), rm1);
  float fx = floorf(px), fy = floorf(py), fz = floorf(pz);
  float wx = px - fx, wy = py - fy, wz = pz - fz;
  int ix0 = (int)fx, iy0 = (int)fy, iz0 = (int)fz;
  int ix1 = min(ix0 + 1, r1), iy1 = min(iy0 + 1, r1), iz1 = min(iz0 + 1, r1);

  // Per-dim index partials. Level 0 (dense): x*256+y*16+z has disjoint bit
  // fields, so XOR == ADD -> same combine path as the hash levels.
  const bool dl = (lvl == 0);
  unsigned hx0, hx1, hy0, hy1, hz0, hz1;
  if (dl) {
    hx0 = (unsigned)ix0 << 8; hx1 = (unsigned)ix1 << 8;
    hy0 = (unsigned)iy0 << 4; hy1 = (unsigned)iy1 << 4;
    hz0 = (unsigned)iz0;      hz1 = (unsigned)iz1;
  } else {
    hx0 = (unsigned)ix0;      hx1 = (unsigned)ix1;        // prime[0] = 1
    hy0 = (unsigned)iy0 * P2; hy1 = (unsigned)iy1 * P2;
    hz0 = (unsigned)iz0 * P3; hz1 = (unsigned)iz1 * P3;
  }

  unsigned idx[8];
  float wgt[8];
#pragma unroll
  for (int c = 0; c < 8; ++c) {
    unsigned hx = (c & 4) ? hx1 : hx0;
    unsigned hy = (c & 2) ? hy1 : hy0;
    unsigned hz = (c & 1) ? hz1 : hz0;
    idx[c] = (hx ^ hy ^ hz) & TMASK;   // mask is a no-op for dense (<=4095)
    float a = (c & 4) ? wx : 1.0f - wx;
    float b = (c & 2) ? wy : 1.0f - wy;
    float d = (c & 1) ? wz : 1.0f - wz;
    wgt[c] = a * b * d;
  }

  float acc0 = 0.0f, acc1 = 0.0f;
  if (XP) {
    const float2* tab = xtab + (dl ? 0 : (4096 + (size_t)(lvl - 1) * TS));
    float2 v[8];
#pragma unroll
    for (int c = 0; c < 8; ++c) v[c] = tab[idx[c]];
#pragma unroll
    for (int c = 0; c < 8; ++c) {
      acc0 = fmaf(v[c].x, wgt[c], acc0);
      acc1 = fmaf(v[c].y, wgt[c], acc1);
    }
  } else {
    const float* t0;
    unsigned fs;
    if (dl) { t0 = dense; fs = 4096; }
    else    { t0 = tables + (size_t)(lvl - 1) * (2 * TS); fs = TS; }
    float v0[8], v1[8];
#pragma unroll
    for (int c = 0; c < 8; ++c) { v0[c] = t0[idx[c]]; v1[c] = t0[fs + idx[c]]; }
#pragma unroll
    for (int c = 0; c < 8; ++c) {
      acc0 = fmaf(v0[c], wgt[c], acc0);
      acc1 = fmaf(v1[c], wgt[c], acc1);
    }
  }

  // out[n, lvl*2 .. lvl*2+1] ; row = 32 floats = 16 float2
  out[(size_t)n * 16 + lvl] = make_float2(acc0, acc1);
}

extern "C" void kernel_launch(void* const* d_in, const int* in_sizes, int n_in,
                              void* d_out, int out_size, void* d_ws, size_t ws_size,
                              hipStream_t stream) {
  const float* coords = (const float*)d_in[0];
  const float* dense  = (const float*)d_in[1];
  const float* tables = (const float*)d_in[2];
  float2* out = (float2*)d_out;
  const int npts = in_sizes[0] / 3;
  const int eblocks = (npts + 15) / 16;
  const size_t need = (size_t)(4096 + 15 * TS) * sizeof(float2);

  if (ws_size >= need) {
    float2* ws = (float2*)d_ws;
    const int tblocks = (15 * TS + 4096 + 255) / 256;
    hipLaunchKernelGGL(xpose_kernel, dim3(tblocks), dim3(256), 0, stream,
                       dense, tables, ws);
    hipLaunchKernelGGL((encode_kernel<true>), dim3(eblocks), dim3(256), 0, stream,
                       coords, dense, tables, ws, out, npts);
  } else {
    hipLaunchKernelGGL((encode_kernel<false>), dim3(eblocks), dim3(256), 0, stream,
                       coords, dense, tables, (const float2*)nullptr, out, npts);
  }
}

// Round 2
// 1497.427 us; speedup vs baseline: 1.2445x; 1.2445x over previous
//
#include <hip/hip_runtime.h>

#define TS 262144          // TABLE_SIZE = 2^18
#define TMASK (TS - 1)
#define P2 2654435761u
#define P3 805459861u

// Pre-pass: transpose tables [F,T] -> [T,F] (float2) into workspace.
// ws layout (float2 units): [0,4096) dense grid, [4096, 4096+15*TS) hash levels 1..15.
__global__ __launch_bounds__(256) void xpose_kernel(
    const float* __restrict__ dense, const float* __restrict__ tables,
    float2* __restrict__ ws) {
  int i = blockIdx.x * 256 + threadIdx.x;
  const int total = 15 * TS;
  if (i < total) {
    int l = i >> 18;
    int h = i & TMASK;
    const float* t = tables + (size_t)l * (2 * TS);
    ws[4096 + i] = make_float2(t[h], t[TS + h]);
  } else {
    int j = i - total;
    if (j < 4096) ws[j] = make_float2(dense[j], dense[4096 + j]);
  }
}

// Main kernel: thread = point; LEVELS IN SEQUENCE with a per-level barrier so
// all resident waves gather from (roughly) one 2MB table at a time -> each
// XCD's 4MB L2 keeps the current table resident (R1 showed 5.7GB fabric
// fetch when all 16 levels were concurrently live).
template <bool XP>
__global__ __launch_bounds__(256) void encode_kernel(
    const float* __restrict__ coords,
    const float* __restrict__ dense,       // original [2,16,16,16] (fallback)
    const float* __restrict__ tables,      // original [15,2,TS]    (fallback)
    const float2* __restrict__ xtab,       // transposed ws (XP path)
    float4* __restrict__ out, int npts) {
  constexpr int RESA[16] = {16, 20, 25, 32, 40, 50, 64, 80,
                            101, 128, 161, 203, 256, 322, 406, 512};
  __shared__ float s_c[768];   // 256 points x 3 coords
  const int tid = threadIdx.x;
  const int pbase = blockIdx.x * 256;

  // Coalesced coord staging: s_c[k] = coords[pbase*3 + k]
#pragma unroll
  for (int j = 0; j < 3; ++j) {
    int gi = pbase * 3 + j * 256 + tid;
    s_c[j * 256 + tid] = (gi < npts * 3) ? __builtin_nontemporal_load(&coords[gi]) : 0.0f;
  }
  __syncthreads();

  const int n = pbase + tid;
  const bool valid = n < npts;
  // stride-3 LDS read: 2-way bank aliasing only (free on gfx950)
  const float cxn = (s_c[tid * 3 + 0] + 1.0f) * 0.5f;
  const float cyn = (s_c[tid * 3 + 1] + 1.0f) * 0.5f;
  const float czn = (s_c[tid * 3 + 2] + 1.0f) * 0.5f;

  float acc[32];

#pragma unroll
  for (int lvl = 0; lvl < 16; ++lvl) {
    const int res = RESA[lvl];
    const int r1 = res - 1;
    const float rm1 = (float)r1;

    float px = fminf(fmaxf(cxn * rm1, 0.0f), rm1);
    float py = fminf(fmaxf(cyn * rm1, 0.0f), rm1);
    float pz = fminf(fmaxf(czn * rm1, 0.0f), rm1);
    float fx = floorf(px), fy = floorf(py), fz = floorf(pz);
    float wx = px - fx, wy = py - fy, wz = pz - fz;
    int ix0 = (int)fx, iy0 = (int)fy, iz0 = (int)fz;
    int ix1 = min(ix0 + 1, r1), iy1 = min(iy0 + 1, r1), iz1 = min(iz0 + 1, r1);

    // Per-dim hash partials. Level 0 (dense): x*256+y*16+z has disjoint bit
    // fields, so XOR == ADD -> same combine path as hash levels.
    unsigned hx0, hx1, hy0, hy1, hz0, hz1;
    if (lvl == 0) {
      hx0 = (unsigned)ix0 << 8; hx1 = (unsigned)ix1 << 8;
      hy0 = (unsigned)iy0 << 4; hy1 = (unsigned)iy1 << 4;
      hz0 = (unsigned)iz0;      hz1 = (unsigned)iz1;
    } else {
      hx0 = (unsigned)ix0;      hx1 = (unsigned)ix1;      // prime[0] = 1
      hy0 = (unsigned)iy0 * P2; hy1 = (unsigned)iy1 * P2;
      hz0 = (unsigned)iz0 * P3; hz1 = (unsigned)iz1 * P3;
    }

    unsigned idx[8];
    float wgt[8];
#pragma unroll
    for (int c = 0; c < 8; ++c) {
      unsigned hx = (c & 4) ? hx1 : hx0;
      unsigned hy = (c & 2) ? hy1 : hy0;
      unsigned hz = (c & 1) ? hz1 : hz0;
      idx[c] = (hx ^ hy ^ hz) & TMASK;   // mask is a no-op for dense (<=4095)
      float a = (c & 4) ? wx : 1.0f - wx;
      float b = (c & 2) ? wy : 1.0f - wy;
      float d = (c & 1) ? wz : 1.0f - wz;
      wgt[c] = a * b * d;
    }

    float a0 = 0.0f, a1 = 0.0f;
    if (XP) {
      const float2* tab = (lvl == 0) ? xtab : (xtab + 4096 + (size_t)(lvl - 1) * TS);
      float2 v[8];
#pragma unroll
      for (int c = 0; c < 8; ++c) v[c] = tab[idx[c]];
#pragma unroll
      for (int c = 0; c < 8; ++c) {
        a0 = fmaf(v[c].x, wgt[c], a0);
        a1 = fmaf(v[c].y, wgt[c], a1);
      }
    } else {
      const float* t0 = (lvl == 0) ? dense : (tables + (size_t)(lvl - 1) * (2 * TS));
      const unsigned fs = (lvl == 0) ? 4096u : (unsigned)TS;
      float v0[8], v1[8];
#pragma unroll
      for (int c = 0; c < 8; ++c) { v0[c] = t0[idx[c]]; v1[c] = t0[fs + idx[c]]; }
#pragma unroll
      for (int c = 0; c < 8; ++c) {
        a0 = fmaf(v0[c], wgt[c], a0);
        a1 = fmaf(v1[c], wgt[c], a1);
      }
    }
    acc[2 * lvl + 0] = a0;
    acc[2 * lvl + 1] = a1;

    // Keep the block's waves lockstepped on the level sequence so the
    // CU/XCD-level instantaneous table working set stays ~one level.
    __syncthreads();
  }

  if (valid) {
    float4* o = out + (size_t)n * 8;   // 128B contiguous row per thread
#pragma unroll
    for (int j = 0; j < 8; ++j)
      o[j] = make_float4(acc[4 * j + 0], acc[4 * j + 1], acc[4 * j + 2], acc[4 * j + 3]);
  }
}

extern "C" void kernel_launch(void* const* d_in, const int* in_sizes, int n_in,
                              void* d_out, int out_size, void* d_ws, size_t ws_size,
                              hipStream_t stream) {
  const float* coords = (const float*)d_in[0];
  const float* dense  = (const float*)d_in[1];
  const float* tables = (const float*)d_in[2];
  float4* out = (float4*)d_out;
  const int npts = in_sizes[0] / 3;
  const int eblocks = (npts + 255) / 256;
  const size_t need = (size_t)(4096 + 15 * TS) * sizeof(float2);

  if (ws_size >= need) {
    float2* ws = (float2*)d_ws;
    const int tblocks = (15 * TS + 4096 + 255) / 256;
    hipLaunchKernelGGL(xpose_kernel, dim3(tblocks), dim3(256), 0, stream,
                       dense, tables, ws);
    hipLaunchKernelGGL((encode_kernel<true>), dim3(eblocks), dim3(256), 0, stream,
                       coords, dense, tables, ws, out, npts);
  } else {
    hipLaunchKernelGGL((encode_kernel<false>), dim3(eblocks), dim3(256), 0, stream,
                       coords, dense, tables, (const float2*)nullptr, out, npts);
  }
}